// Round 11
// baseline (179.064 us; speedup 1.0000x reference)
//
#include <hip/hip_runtime.h>
#include <math.h>

#define NUM_HEADS 16
#define HEAD_DIM 64

typedef __bf16 bf16x8 __attribute__((ext_vector_type(8)));
typedef short shortx4 __attribute__((ext_vector_type(4)));
typedef float floatx4 __attribute__((ext_vector_type(4)));

#if __has_builtin(__builtin_amdgcn_exp2f)
#define EXP2(x) __builtin_amdgcn_exp2f(x)
#else
#define EXP2(x) exp2f(x)
#endif

__device__ __forceinline__ unsigned short f2b(float f) {
  unsigned int u = __float_as_uint(f);
  u += 0x7fffu + ((u >> 16) & 1u);
  return (unsigned short)(u >> 16);
}

__device__ __forceinline__ void async16(const void* g, void* l) {
  __builtin_amdgcn_global_load_lds(
      (const __attribute__((address_space(1))) unsigned int*)g,
      (__attribute__((address_space(3))) unsigned int*)l, 16, 0, 0);
}

__device__ __forceinline__ void cvt4(const float* in, unsigned short* out, int i) {
  float4 v = ((const float4*)in)[i];
  ushort4 o;
  o.x = f2b(v.x); o.y = f2b(v.y); o.z = f2b(v.z); o.w = f2b(v.w);
  ((ushort4*)out)[i] = o;
}

// ------------- prep: all converts + rope table in ONE launch -------------
// z=0: X (4 reps); z=1..4: weights; z=5: rope cos/sin table.
__global__ void prep(const float* __restrict__ x,
                     const float* __restrict__ w0, const float* __restrict__ w1,
                     const float* __restrict__ w2, const float* __restrict__ w3,
                     const int* __restrict__ pos,
                     unsigned short* Xb, unsigned short* o0, unsigned short* o1,
                     unsigned short* o2, unsigned short* o3,
                     float* __restrict__ tab, int xq, int w4, int ntab) {
  int i = blockIdx.x * 256 + threadIdx.x;
  int z = blockIdx.y;
  if (z == 0) {
    if (i < xq) {
#pragma unroll
      for (int rep = 0; rep < 4; ++rep) cvt4(x, Xb, rep * xq + i);
    }
  } else if (z <= 4) {
    if (i < w4) {
      const float* in = (z == 1) ? w0 : (z == 2) ? w1 : (z == 3) ? w2 : w3;
      unsigned short* out = (z == 1) ? o0 : (z == 2) ? o1 : (z == 3) ? o2 : o3;
      cvt4(in, out, i);
    }
  } else {
    if (i < ntab) {
      int fi = i & 31, s = i >> 5;
      float inv = expf(-0.28782313662425575f * (float)fi);
      float ang = (float)pos[s] * inv;
      float sn, cs;
      sincosf(ang, &sn, &cs);
      tab[i * 2] = cs;
      tab[i * 2 + 1] = sn;
    }
  }
}

// ---------------- bf16 GEMM, C = A * B^T (C^T frags) ----------------
// R10-verbatim: BK=64 via 2-half unroll of the verified BK=32 template
// (barriers 32->16, MFMA per barrier doubled; dropped QKV GEMM below the
// 43us fill cutoff). Ledger: counted-vmcnt (R7) and 256x128 8-wave (R8)
// neutral; BK=64 drain-amortization is the working 2-phase lever.
// MODE 0 (MT=128): bf16 out; z==0 -> Q with RoPE*(1/8*log2e);
//                  z==1 -> K with RoPE; z==2 -> V transposed (B,H,HD,S).
// MODE 1: fp32 out row-major (M,N), MT=64.
template <int MODE, int MT>
__global__ __launch_bounds__(256, MODE == 1 ? 4 : 2)
void gemm_bt(const unsigned short* __restrict__ A,
             const unsigned short* __restrict__ B0,
             const unsigned short* __restrict__ B1,
             const unsigned short* __restrict__ B2,
             void* out0v, void* out1v, void* out2v,
             const float* __restrict__ ctab,
             int M, int N, int K, int S) {
  constexpr int ABUF = (MT / 16) * 512;
  constexpr int BBUF = 8 * 512;
  __shared__ unsigned short As[2 * ABUF];
  __shared__ unsigned short Bs[2 * BBUF];
  const int tid = threadIdx.x;
  const int lane = tid & 63;
  const int w = tid >> 6;
  const int lane16 = lane & 15;
  const int g = lane >> 4;
  const int wm = w >> 1, wn = w & 1;
  const int m0 = blockIdx.y * MT;
  const int n0 = blockIdx.x * 128;
  const unsigned short* Bp = (blockIdx.z == 0) ? B0 : (blockIdx.z == 1 ? B1 : B2);
  constexpr int MTILES = MT / 32;

  const floatx4 vzero = {0.f, 0.f, 0.f, 0.f};
  floatx4 acc[MTILES][4];
#pragma unroll
  for (int i = 0; i < MTILES; i++)
#pragma unroll
    for (int j = 0; j < 4; j++) acc[i][j] = vzero;

  const int ar = lane >> 2;
  const int ac = (lane & 3) * 8;

  for (int k0 = 0; k0 < K; k0 += 64) {
#pragma unroll
    for (int h2 = 0; h2 < 2; ++h2) {
      const int kk = k0 + h2 * 32;
      if constexpr (MT == 128) {
#pragma unroll
        for (int c = 0; c < 2; c++) {
          int chunk = w * 2 + c;
          async16(A  + (size_t)(m0 + chunk * 16 + ar) * K + kk + ac, As + h2 * ABUF + chunk * 512);
          async16(Bp + (size_t)(n0 + chunk * 16 + ar) * K + kk + ac, Bs + h2 * BBUF + chunk * 512);
        }
      } else {
        async16(A  + (size_t)(m0 + w * 16 + ar) * K + kk + ac, As + h2 * ABUF + w * 512);
        async16(Bp + (size_t)(n0 + w * 16 + ar) * K + kk + ac, Bs + h2 * BBUF + w * 512);
        async16(Bp + (size_t)(n0 + (w + 4) * 16 + ar) * K + kk + ac, Bs + h2 * BBUF + (w + 4) * 512);
      }
    }
    __syncthreads();
#pragma unroll
    for (int h2 = 0; h2 < 2; ++h2) {
      const unsigned short* Ab = As + h2 * ABUF;
      const unsigned short* Bb = Bs + h2 * BBUF;
      bf16x8 a[MTILES], b[4];
#pragma unroll
      for (int mt = 0; mt < MTILES; mt++)
        a[mt] = *(const bf16x8*)&Ab[(wm * (MT / 2) + mt * 16 + lane16) * 32 + g * 8];
#pragma unroll
      for (int nt = 0; nt < 4; nt++)
        b[nt] = *(const bf16x8*)&Bb[(wn * 64 + nt * 16 + lane16) * 32 + g * 8];
#pragma unroll
      for (int mt = 0; mt < MTILES; mt++)
#pragma unroll
        for (int nt = 0; nt < 4; nt++)
          acc[mt][nt] = __builtin_amdgcn_mfma_f32_16x16x32_bf16(b[nt], a[mt], acc[mt][nt], 0, 0, 0);
    }
    __syncthreads();
  }

  if (MODE == 0) {
    if (blockIdx.z < 2) {
      unsigned short* outp = (unsigned short*)((blockIdx.z == 0) ? out0v : out1v);
      // Q scale folds 1/sqrt(64) AND log2(e) so softmax can use raw v_exp_f32.
      const float qs = (blockIdx.z == 0) ? 0.18033688011112042f : 1.0f;
#pragma unroll
      for (int mt = 0; mt < MTILES; mt++) {
        int m = m0 + wm * (MT / 2) + mt * 16 + lane16;
        int bb = m / S, s = m - bb * S;
        const float* crow = ctab + (size_t)s * 64;
#pragma unroll
        for (int nt = 0; nt < 4; nt++) {
          int n = n0 + wn * 64 + nt * 16 + g * 4;
          int h = n >> 6, dl = n & 63;
          floatx4 v = acc[mt][nt];
          float4 cs = *(const float4*)&crow[dl];
          float r0 = (v[0] * cs.x - v[1] * cs.y) * qs;
          float r1 = (v[0] * cs.y + v[1] * cs.x) * qs;
          float r2 = (v[2] * cs.z - v[3] * cs.w) * qs;
          float r3 = (v[2] * cs.w + v[3] * cs.z) * qs;
          shortx4 st;
          st[0] = (short)f2b(r0); st[1] = (short)f2b(r1);
          st[2] = (short)f2b(r2); st[3] = (short)f2b(r3);
          *(shortx4*)&outp[(((size_t)(bb * NUM_HEADS + h) * S + s) << 6) + dl] = st;
        }
      }
    } else {
      // z==2: V written transposed -> Vt (BH, 64, S).
      unsigned short* outp = (unsigned short*)out2v;
#pragma unroll
      for (int mt = 0; mt < MTILES; mt++) {
        int m = m0 + wm * (MT / 2) + mt * 16 + lane16;
        int bb = m / S, s = m - bb * S;
#pragma unroll
        for (int nt = 0; nt < 4; nt++) {
          int n = n0 + wn * 64 + nt * 16 + g * 4;
          int bh = bb * NUM_HEADS + (n >> 6);
          int dl = n & 63;
          size_t dbase = ((size_t)bh * 64 + dl) * S + s;
#pragma unroll
          for (int r = 0; r < 4; r++)
            outp[dbase + (size_t)r * S] = f2b(acc[mt][nt][r]);
        }
      }
    }
  } else {
    float* outp = (float*)out0v;
#pragma unroll
    for (int mt = 0; mt < MTILES; mt++) {
      int m = m0 + wm * (MT / 2) + mt * 16 + lane16;
#pragma unroll
      for (int nt = 0; nt < 4; nt++) {
        int n = n0 + wn * 64 + nt * 16 + g * 4;
        *(floatx4*)&outp[(size_t)m * N + n] = acc[mt][nt];
      }
    }
  }
}

// ---------------- causal flash attention v12: 5-deep pipeline ------------
// R9/R10 flash (paired q-tiles {qa, NT-1-qa}, counted vmcnt, XCD swizzle,
// setprio) with prefetch distance 3 -> 4: 5-deep LDS buffers (80 KB =
// exactly 2 blocks/CU), steady vmcnt(12). Mechanism: per-iter compute
// ~350 cy -> distance-4 gives ~1500 cy stage->consume cover, above the
// ~900 cy HBM cold-miss latency that distance-3 (~1100 cy) only marginally
// covers (R9 FETCH=12.4 MB: ~half of unique K/V misses to HBM). R8 lesson:
// distance is the dominant variable (distance-2 was +60%).
__global__ __launch_bounds__(256, 2)
void flash_attn7(const unsigned short* __restrict__ Q,
                 const unsigned short* __restrict__ Kv,
                 const unsigned short* __restrict__ Vt,
                 unsigned short* __restrict__ Oattn, int S) {
  __shared__ unsigned short Ks[5 * 4096];
  __shared__ unsigned short Vs[5 * 4096];
  const int tid = threadIdx.x;
  const int lane = tid & 63;
  const int w = tid >> 6;
  const int lane16 = lane & 15;
  const int g = lane >> 4;
  const int sw = lane16 & 7;
  const int NT = S >> 6;
  int qa, bh;
  {
    int nx = gridDim.x, ny = gridDim.y;
    int flat = blockIdx.y * nx + blockIdx.x;
    if ((ny & 7) == 0) {
      int xcd = flat & 7;          // linear dispatch round-robins XCDs
      int idx = flat >> 3;
      int per = ny >> 3;           // bh per XCD
      bh = xcd * per + (idx % per);
      qa = idx / per;              // bijective: idx in [0, nx*per)
    } else {
      qa = blockIdx.x; bh = blockIdx.y;
    }
  }
  const int qb = NT - 1 - qa;          // mirror tile
  const int b = bh >> 4, h = bh & 15;
  const size_t kbase = (size_t)bh * S * HEAD_DIM;
  const unsigned short* Kbase = Kv + kbase;
  const unsigned short* Vtbase = Vt + (size_t)bh * HEAD_DIM * S;
  const int qrowA = qa * 64 + w * 16;
  const int qrowB = qb * 64 + w * 16;

  bf16x8 qA0, qA1, qB0, qB1;
  {
    const unsigned short* qp = Q + kbase + (size_t)(qrowA + lane16) * HEAD_DIM + g * 8;
    qA0 = *(const bf16x8*)qp;
    qA1 = *(const bf16x8*)(qp + 32);
    qp = Q + kbase + (size_t)(qrowB + lane16) * HEAD_DIM + g * 8;
    qB0 = *(const bf16x8*)qp;
    qB1 = *(const bf16x8*)(qp + 32);
  }

  const int ci0 = w * 64 + lane;
  const int ci1 = ci0 + 256;
  const int r0 = ci0 >> 3, j0 = (ci0 & 7) ^ (r0 & 7);
  const int r1 = ci1 >> 3, j1 = (ci1 & 7) ^ (r1 & 7);
  const unsigned short* kS0 = Kbase + r0 * HEAD_DIM + j0 * 8;
  const unsigned short* kS1 = Kbase + r1 * HEAD_DIM + j1 * 8;
  const unsigned short* vS0 = Vtbase + (size_t)r0 * S + j0 * 8;
  const unsigned short* vS1 = Vtbase + (size_t)r1 * S + j1 * 8;
  unsigned short* kD0 = Ks + ci0 * 8;
  unsigned short* kD1 = Ks + ci1 * 8;
  unsigned short* vD0 = Vs + ci0 * 8;
  unsigned short* vD1 = Vs + ci1 * 8;

  auto stage = [&](int t, int sbi) {
    int koff = t * 4096;
    int voff = t * 64;
    int doff = sbi * 4096;
    async16(kS0 + koff, kD0 + doff);
    async16(kS1 + koff, kD1 + doff);
    async16(vS0 + voff, vD0 + doff);
    async16(vS1 + voff, vD1 + doff);
  };

  const floatx4 vzero = {0.f, 0.f, 0.f, 0.f};
  floatx4 oA[4], oB[4];
#pragma unroll
  for (int i = 0; i < 4; i++) { oA[i] = vzero; oB[i] = vzero; }
  float lA = 0.f, lB = 0.f;

  // prologue: 4 tiles in flight (qb >= NT/2 >= 4 for all real shapes;
  // guarded anyway)
  stage(0, 0);
  __builtin_amdgcn_sched_barrier(0);
  if (qb >= 1) stage(1, 1);
  __builtin_amdgcn_sched_barrier(0);
  if (qb >= 2) stage(2, 2);
  __builtin_amdgcn_sched_barrier(0);
  if (qb >= 3) stage(3, 3);
  __builtin_amdgcn_sched_barrier(0);

  int bi = 0, si = 4;
  for (int t = 0; t <= qb; ++t) {
    const int rem = qb - t;
    // wait only for tile t's 4 loads (oldest group); keep rest in flight
    if (rem >= 3)      asm volatile("s_waitcnt vmcnt(12)" ::: "memory");
    else if (rem == 2) asm volatile("s_waitcnt vmcnt(8)" ::: "memory");
    else if (rem == 1) asm volatile("s_waitcnt vmcnt(4)" ::: "memory");
    else               asm volatile("s_waitcnt vmcnt(0)" ::: "memory");
    __builtin_amdgcn_sched_barrier(0);
    __builtin_amdgcn_s_barrier();
    __builtin_amdgcn_sched_barrier(0);
    if (t + 4 <= qb) stage(t + 4, si);
    __builtin_amdgcn_sched_barrier(0);

    const unsigned short* Kb_ = Ks + bi * 4096;
    const unsigned short* Vb_ = Vs + bi * 4096;
    const bool doA = (t <= qa);

    // shared K fragments (8 ds_read_b128 serve both q-tiles)
    bf16x8 kf0[4], kf1[4];
#pragma unroll
    for (int c = 0; c < 4; ++c) {
      int rr = c * 16 + lane16;
      kf0[c] = *(const bf16x8*)&Kb_[(rr * 8 + (g ^ sw)) * 8];
      kf1[c] = *(const bf16x8*)&Kb_[(rr * 8 + ((4 + g) ^ sw)) * 8];
    }

    floatx4 scB[4];
    __builtin_amdgcn_s_setprio(1);
#pragma unroll
    for (int c = 0; c < 4; ++c) {
      floatx4 s = vzero;
      s = __builtin_amdgcn_mfma_f32_16x16x32_bf16(kf0[c], qB0, s, 0, 0, 0);
      s = __builtin_amdgcn_mfma_f32_16x16x32_bf16(kf1[c], qB1, s, 0, 0, 0);
      scB[c] = s;
    }
    __builtin_amdgcn_s_setprio(0);
    if (t == qb) {
      const int i = qrowB + lane16;
      const int jb = t * 64;
#pragma unroll
      for (int c = 0; c < 4; ++c)
#pragma unroll
        for (int r = 0; r < 4; ++r)
          if (jb + c * 16 + g * 4 + r > i) scB[c][r] = -INFINITY;
    }
    shortx4 pcB[4], pcA[4];
#pragma unroll
    for (int c = 0; c < 4; ++c) {
      float p0 = EXP2(scB[c][0]);
      float p1 = EXP2(scB[c][1]);
      float p2 = EXP2(scB[c][2]);
      float p3 = EXP2(scB[c][3]);
      lB += (p0 + p1) + (p2 + p3);
      union { unsigned int u[2]; shortx4 s4; } pu;
      pu.u[0] = __builtin_amdgcn_perm(__float_as_uint(p1), __float_as_uint(p0), 0x07060302u);
      pu.u[1] = __builtin_amdgcn_perm(__float_as_uint(p3), __float_as_uint(p2), 0x07060302u);
      pcB[c] = pu.s4;
    }

    if (doA) {
      floatx4 scA[4];
      __builtin_amdgcn_s_setprio(1);
#pragma unroll
      for (int c = 0; c < 4; ++c) {
        floatx4 s = vzero;
        s = __builtin_amdgcn_mfma_f32_16x16x32_bf16(kf0[c], qA0, s, 0, 0, 0);
        s = __builtin_amdgcn_mfma_f32_16x16x32_bf16(kf1[c], qA1, s, 0, 0, 0);
        scA[c] = s;
      }
      __builtin_amdgcn_s_setprio(0);
      if (t == qa) {
        const int i = qrowA + lane16;
        const int jb = t * 64;
#pragma unroll
        for (int c = 0; c < 4; ++c)
#pragma unroll
          for (int r = 0; r < 4; ++r)
            if (jb + c * 16 + g * 4 + r > i) scA[c][r] = -INFINITY;
      }
#pragma unroll
      for (int c = 0; c < 4; ++c) {
        float p0 = EXP2(scA[c][0]);
        float p1 = EXP2(scA[c][1]);
        float p2 = EXP2(scA[c][2]);
        float p3 = EXP2(scA[c][3]);
        lA += (p0 + p1) + (p2 + p3);
        union { unsigned int u[2]; shortx4 s4; } pu;
        pu.u[0] = __builtin_amdgcn_perm(__float_as_uint(p1), __float_as_uint(p0), 0x07060302u);
        pu.u[1] = __builtin_amdgcn_perm(__float_as_uint(p3), __float_as_uint(p2), 0x07060302u);
        pcA[c] = pu.s4;
      }
      // PV for both tiles: each vf ds_read feeds TWO mfmas
      __builtin_amdgcn_s_setprio(1);
#pragma unroll
      for (int nt = 0; nt < 4; ++nt) {
        int rv = nt * 16 + lane16;
#pragma unroll
        for (int c = 0; c < 4; ++c) {
          shortx4 vf = *(const shortx4*)&Vb_[(rv * 8 + ((c * 2 + (g >> 1)) ^ sw)) * 8 + (g & 1) * 4];
          oB[nt] = __builtin_amdgcn_mfma_f32_16x16x16bf16_1k(vf, pcB[c], oB[nt], 0, 0, 0);
          oA[nt] = __builtin_amdgcn_mfma_f32_16x16x16bf16_1k(vf, pcA[c], oA[nt], 0, 0, 0);
        }
      }
      __builtin_amdgcn_s_setprio(0);
    } else {
      __builtin_amdgcn_s_setprio(1);
#pragma unroll
      for (int nt = 0; nt < 4; ++nt) {
        int rv = nt * 16 + lane16;
#pragma unroll
        for (int c = 0; c < 4; ++c) {
          shortx4 vf = *(const shortx4*)&Vb_[(rv * 8 + ((c * 2 + (g >> 1)) ^ sw)) * 8 + (g & 1) * 4];
          oB[nt] = __builtin_amdgcn_mfma_f32_16x16x16bf16_1k(vf, pcB[c], oB[nt], 0, 0, 0);
        }
      }
      __builtin_amdgcn_s_setprio(0);
    }

    bi = (bi == 4) ? 0 : bi + 1;
    si = (si == 4) ? 0 : si + 1;
  }

  // epilogue: reduce l over g-groups, normalize, store bf16
  {
    float l = lA;
    l += __shfl_xor(l, 16, 64);
    l += __shfl_xor(l, 32, 64);
    float inv = 1.0f / l;
    int srow = qrowA + lane16;
    size_t rowb = ((size_t)b * S + srow) * 1024 + h * 64;
#pragma unroll
    for (int nt = 0; nt < 4; ++nt) {
      shortx4 st;
#pragma unroll
      for (int r = 0; r < 4; ++r) st[r] = (short)f2b(oA[nt][r] * inv);
      *(shortx4*)&Oattn[rowb + nt * 16 + g * 4] = st;
    }
  }
  {
    float l = lB;
    l += __shfl_xor(l, 16, 64);
    l += __shfl_xor(l, 32, 64);
    float inv = 1.0f / l;
    int srow = qrowB + lane16;
    size_t rowb = ((size_t)b * S + srow) * 1024 + h * 64;
#pragma unroll
    for (int nt = 0; nt < 4; ++nt) {
      shortx4 st;
#pragma unroll
      for (int r = 0; r < 4; ++r) st[r] = (short)f2b(oB[nt][r] * inv);
      *(shortx4*)&Oattn[rowb + nt * 16 + g * 4] = st;
    }
  }
}

// ---------------- launcher ----------------
extern "C" void kernel_launch(void* const* d_in, const int* in_sizes, int n_in,
                              void* d_out, int out_size, void* d_ws, size_t ws_size,
                              hipStream_t stream) {
  const float* x  = (const float*)d_in[0];
  const int*  pos = (const int*)d_in[1];
  const float* wq = (const float*)d_in[2];
  const float* wk = (const float*)d_in[3];
  const float* wv = (const float*)d_in[4];
  const float* wo = (const float*)d_in[5];

  const int D = 1024;
  const int S = in_sizes[1];
  const int M = in_sizes[0] / D;       // B*S
  const int B = M / S;
  const int BH = B * NUM_HEADS;

  char* wsb = (char*)d_ws;
  size_t off = 0;
  auto alloc = [&](size_t bytes) {
    char* p = wsb + off;
    off += (bytes + 255) & ~(size_t)255;
    return p;
  };
  unsigned short* Xb   = (unsigned short*)alloc((size_t)M * D * 2);
  unsigned short* Wqb  = (unsigned short*)alloc((size_t)D * D * 2);
  unsigned short* Wkb  = (unsigned short*)alloc((size_t)D * D * 2);
  unsigned short* Wvb  = (unsigned short*)alloc((size_t)D * D * 2);
  unsigned short* Wob  = (unsigned short*)alloc((size_t)D * D * 2);
  unsigned short* Qb   = (unsigned short*)alloc((size_t)M * D * 2);
  unsigned short* Kb   = (unsigned short*)alloc((size_t)M * D * 2);
  unsigned short* Vtb  = (unsigned short*)alloc((size_t)M * D * 2);  // transposed V
  unsigned short* Attn = (unsigned short*)alloc((size_t)M * D * 2);
  float*          Ctab = (float*)alloc((size_t)S * 32 * 2 * 4);
  (void)ws_size;

  {
    int n4x = M * D / 4;
    int xq = n4x / 4;                 // z=0 threads (4 reps each)
    int w4 = D * D / 4;
    int ntab = S * 32;
    int gx = (w4 + 255) / 256;        // >= xq/256 and >= ntab/256
    prep<<<dim3(gx, 6), 256, 0, stream>>>(x, wq, wk, wv, wo, pos,
                                          Xb, Wqb, Wkb, Wvb, Wob, Ctab,
                                          xq, w4, ntab);
  }
  // QKV projections (BK=64 2-half k-loop); z==2 writes V transposed.
  gemm_bt<0, 128><<<dim3(D / 128, M / 128, 3), 256, 0, stream>>>(
      Xb, Wqb, Wkb, Wvb, Qb, Kb, Vtb, Ctab, M, D, D, S);
  // paired causal flash attention, 5-deep counted-vmcnt -> (B*S, D) bf16
  flash_attn7<<<dim3(S / 128, BH), 256, 0, stream>>>(Qb, Kb, Vtb, Attn, S);
  // output projection (64-row tiles -> 512 blocks = 2/CU) -> fp32 d_out
  gemm_bt<1, 64><<<dim3(D / 128, M / 64, 1), 256, 0, stream>>>(
      Attn, Wob, Wob, Wob, d_out, d_out, d_out, Ctab, M, D, D, S);
}

// Round 12
// 176.165 us; speedup vs baseline: 1.0165x; 1.0165x over previous
//
#include <hip/hip_runtime.h>
#include <math.h>

#define NUM_HEADS 16
#define HEAD_DIM 64

typedef __bf16 bf16x8 __attribute__((ext_vector_type(8)));
typedef short shortx4 __attribute__((ext_vector_type(4)));
typedef float floatx4 __attribute__((ext_vector_type(4)));

#if __has_builtin(__builtin_amdgcn_exp2f)
#define EXP2(x) __builtin_amdgcn_exp2f(x)
#else
#define EXP2(x) exp2f(x)
#endif

__device__ __forceinline__ unsigned short f2b(float f) {
  unsigned int u = __float_as_uint(f);
  u += 0x7fffu + ((u >> 16) & 1u);
  return (unsigned short)(u >> 16);
}

__device__ __forceinline__ void async16(const void* g, void* l) {
  __builtin_amdgcn_global_load_lds(
      (const __attribute__((address_space(1))) unsigned int*)g,
      (__attribute__((address_space(3))) unsigned int*)l, 16, 0, 0);
}

__device__ __forceinline__ void cvt4(const float* in, unsigned short* out, int i) {
  float4 v = ((const float4*)in)[i];
  ushort4 o;
  o.x = f2b(v.x); o.y = f2b(v.y); o.z = f2b(v.z); o.w = f2b(v.w);
  ((ushort4*)out)[i] = o;
}

// ------------- prep: all converts + rope table in ONE launch -------------
// z=0: X (4 reps); z=1..4: weights; z=5: rope cos/sin table.
__global__ void prep(const float* __restrict__ x,
                     const float* __restrict__ w0, const float* __restrict__ w1,
                     const float* __restrict__ w2, const float* __restrict__ w3,
                     const int* __restrict__ pos,
                     unsigned short* Xb, unsigned short* o0, unsigned short* o1,
                     unsigned short* o2, unsigned short* o3,
                     float* __restrict__ tab, int xq, int w4, int ntab) {
  int i = blockIdx.x * 256 + threadIdx.x;
  int z = blockIdx.y;
  if (z == 0) {
    if (i < xq) {
#pragma unroll
      for (int rep = 0; rep < 4; ++rep) cvt4(x, Xb, rep * xq + i);
    }
  } else if (z <= 4) {
    if (i < w4) {
      const float* in = (z == 1) ? w0 : (z == 2) ? w1 : (z == 3) ? w2 : w3;
      unsigned short* out = (z == 1) ? o0 : (z == 2) ? o1 : (z == 3) ? o2 : o3;
      cvt4(in, out, i);
    }
  } else {
    if (i < ntab) {
      int fi = i & 31, s = i >> 5;
      float inv = expf(-0.28782313662425575f * (float)fi);
      float ang = (float)pos[s] * inv;
      float sn, cs;
      sincosf(ang, &sn, &cs);
      tab[i * 2] = cs;
      tab[i * 2 + 1] = sn;
    }
  }
}

// ---------------- bf16 GEMM, C = A * B^T (C^T frags) ----------------
// R10-verbatim: BK=64 via 2-half unroll of the verified BK=32 template
// (barriers 32->16, MFMA per barrier doubled). Ledger: counted-vmcnt (R7)
// and 256x128 8-wave (R8) neutral; BK=64 drain-amortization works.
// MODE 0 (MT=128): bf16 out; z==0 -> Q with RoPE*(1/8*log2e);
//                  z==1 -> K with RoPE; z==2 -> V transposed (B,H,HD,S).
// MODE 1: fp32 out row-major (M,N), MT=64.
template <int MODE, int MT>
__global__ __launch_bounds__(256, MODE == 1 ? 4 : 2)
void gemm_bt(const unsigned short* __restrict__ A,
             const unsigned short* __restrict__ B0,
             const unsigned short* __restrict__ B1,
             const unsigned short* __restrict__ B2,
             void* out0v, void* out1v, void* out2v,
             const float* __restrict__ ctab,
             int M, int N, int K, int S) {
  constexpr int ABUF = (MT / 16) * 512;
  constexpr int BBUF = 8 * 512;
  __shared__ unsigned short As[2 * ABUF];
  __shared__ unsigned short Bs[2 * BBUF];
  const int tid = threadIdx.x;
  const int lane = tid & 63;
  const int w = tid >> 6;
  const int lane16 = lane & 15;
  const int g = lane >> 4;
  const int wm = w >> 1, wn = w & 1;
  const int m0 = blockIdx.y * MT;
  const int n0 = blockIdx.x * 128;
  const unsigned short* Bp = (blockIdx.z == 0) ? B0 : (blockIdx.z == 1 ? B1 : B2);
  constexpr int MTILES = MT / 32;

  const floatx4 vzero = {0.f, 0.f, 0.f, 0.f};
  floatx4 acc[MTILES][4];
#pragma unroll
  for (int i = 0; i < MTILES; i++)
#pragma unroll
    for (int j = 0; j < 4; j++) acc[i][j] = vzero;

  const int ar = lane >> 2;
  const int ac = (lane & 3) * 8;

  for (int k0 = 0; k0 < K; k0 += 64) {
#pragma unroll
    for (int h2 = 0; h2 < 2; ++h2) {
      const int kk = k0 + h2 * 32;
      if constexpr (MT == 128) {
#pragma unroll
        for (int c = 0; c < 2; c++) {
          int chunk = w * 2 + c;
          async16(A  + (size_t)(m0 + chunk * 16 + ar) * K + kk + ac, As + h2 * ABUF + chunk * 512);
          async16(Bp + (size_t)(n0 + chunk * 16 + ar) * K + kk + ac, Bs + h2 * BBUF + chunk * 512);
        }
      } else {
        async16(A  + (size_t)(m0 + w * 16 + ar) * K + kk + ac, As + h2 * ABUF + w * 512);
        async16(Bp + (size_t)(n0 + w * 16 + ar) * K + kk + ac, Bs + h2 * BBUF + w * 512);
        async16(Bp + (size_t)(n0 + (w + 4) * 16 + ar) * K + kk + ac, Bs + h2 * BBUF + (w + 4) * 512);
      }
    }
    __syncthreads();
#pragma unroll
    for (int h2 = 0; h2 < 2; ++h2) {
      const unsigned short* Ab = As + h2 * ABUF;
      const unsigned short* Bb = Bs + h2 * BBUF;
      bf16x8 a[MTILES], b[4];
#pragma unroll
      for (int mt = 0; mt < MTILES; mt++)
        a[mt] = *(const bf16x8*)&Ab[(wm * (MT / 2) + mt * 16 + lane16) * 32 + g * 8];
#pragma unroll
      for (int nt = 0; nt < 4; nt++)
        b[nt] = *(const bf16x8*)&Bb[(wn * 64 + nt * 16 + lane16) * 32 + g * 8];
#pragma unroll
      for (int mt = 0; mt < MTILES; mt++)
#pragma unroll
        for (int nt = 0; nt < 4; nt++)
          acc[mt][nt] = __builtin_amdgcn_mfma_f32_16x16x32_bf16(b[nt], a[mt], acc[mt][nt], 0, 0, 0);
    }
    __syncthreads();
  }

  if (MODE == 0) {
    if (blockIdx.z < 2) {
      unsigned short* outp = (unsigned short*)((blockIdx.z == 0) ? out0v : out1v);
      // Q scale folds 1/sqrt(64) AND log2(e) so softmax can use raw v_exp_f32.
      const float qs = (blockIdx.z == 0) ? 0.18033688011112042f : 1.0f;
#pragma unroll
      for (int mt = 0; mt < MTILES; mt++) {
        int m = m0 + wm * (MT / 2) + mt * 16 + lane16;
        int bb = m / S, s = m - bb * S;
        const float* crow = ctab + (size_t)s * 64;
#pragma unroll
        for (int nt = 0; nt < 4; nt++) {
          int n = n0 + wn * 64 + nt * 16 + g * 4;
          int h = n >> 6, dl = n & 63;
          floatx4 v = acc[mt][nt];
          float4 cs = *(const float4*)&crow[dl];
          float r0 = (v[0] * cs.x - v[1] * cs.y) * qs;
          float r1 = (v[0] * cs.y + v[1] * cs.x) * qs;
          float r2 = (v[2] * cs.z - v[3] * cs.w) * qs;
          float r3 = (v[2] * cs.w + v[3] * cs.z) * qs;
          shortx4 st;
          st[0] = (short)f2b(r0); st[1] = (short)f2b(r1);
          st[2] = (short)f2b(r2); st[3] = (short)f2b(r3);
          *(shortx4*)&outp[(((size_t)(bb * NUM_HEADS + h) * S + s) << 6) + dl] = st;
        }
      }
    } else {
      // z==2: V written transposed -> Vt (BH, 64, S).
      unsigned short* outp = (unsigned short*)out2v;
#pragma unroll
      for (int mt = 0; mt < MTILES; mt++) {
        int m = m0 + wm * (MT / 2) + mt * 16 + lane16;
        int bb = m / S, s = m - bb * S;
#pragma unroll
        for (int nt = 0; nt < 4; nt++) {
          int n = n0 + wn * 64 + nt * 16 + g * 4;
          int bh = bb * NUM_HEADS + (n >> 6);
          int dl = n & 63;
          size_t dbase = ((size_t)bh * 64 + dl) * S + s;
#pragma unroll
          for (int r = 0; r < 4; r++)
            outp[dbase + (size_t)r * S] = f2b(acc[mt][nt][r]);
        }
      }
    }
  } else {
    float* outp = (float*)out0v;
#pragma unroll
    for (int mt = 0; mt < MTILES; mt++) {
      int m = m0 + wm * (MT / 2) + mt * 16 + lane16;
#pragma unroll
      for (int nt = 0; nt < 4; nt++) {
        int n = n0 + wn * 64 + nt * 16 + g * 4;
        *(floatx4*)&outp[(size_t)m * N + n] = acc[mt][nt];
      }
    }
  }
}

// ---------------- causal flash attention v13: span-balanced qa remap -----
// R10-verbatim structure (4-deep, counted vmcnt 8/4/0, XCD swizzle,
// setprio) + ONE change: complementary qa remap. Blocks' iteration counts
// vary 17..32 (compute is balanced; loop iterations are not). Dispatch
// model: block flat -> XCD flat&7, CU slot (flat/8)%32, so a CU co-hosts
// flat and flat+256, whose qa_raw differ by exactly 8 (= nx/2). The remap
// qa = qr<8 ? qr : 23-qr makes every co-resident pair's iteration sum
// exactly (NT/2)+... = 49 -- equalizing per-CU span (was up to 56 vs 49
// avg, a ~15% tail).
__global__ __launch_bounds__(256, 2)
void flash_attn7(const unsigned short* __restrict__ Q,
                 const unsigned short* __restrict__ Kv,
                 const unsigned short* __restrict__ Vt,
                 unsigned short* __restrict__ Oattn, int S) {
  __shared__ unsigned short Ks[4 * 4096];
  __shared__ unsigned short Vs[4 * 4096];
  const int tid = threadIdx.x;
  const int lane = tid & 63;
  const int w = tid >> 6;
  const int lane16 = lane & 15;
  const int g = lane >> 4;
  const int sw = lane16 & 7;
  const int NT = S >> 6;
  int qa, bh;
  {
    int nx = gridDim.x, ny = gridDim.y;
    int flat = blockIdx.y * nx + blockIdx.x;
    if ((ny & 7) == 0) {
      int xcd = flat & 7;          // linear dispatch round-robins XCDs
      int idx = flat >> 3;
      int per = ny >> 3;           // bh per XCD
      bh = xcd * per + (idx % per);
      int qr = idx / per;          // [0, nx), bijective
      if ((nx & 1) == 0) {
        int qh = nx >> 1;
        // complementary remap: co-resident blocks (qr, qr+qh) get qa
        // summing to nx-1 -> equal per-CU iteration totals
        qa = (qr < qh) ? qr : (nx - 1) - (qr - qh);
      } else {
        qa = qr;
      }
    } else {
      qa = blockIdx.x; bh = blockIdx.y;
    }
  }
  const int qb = NT - 1 - qa;          // mirror tile
  const int b = bh >> 4, h = bh & 15;
  const size_t kbase = (size_t)bh * S * HEAD_DIM;
  const unsigned short* Kbase = Kv + kbase;
  const unsigned short* Vtbase = Vt + (size_t)bh * HEAD_DIM * S;
  const int qrowA = qa * 64 + w * 16;
  const int qrowB = qb * 64 + w * 16;

  bf16x8 qA0, qA1, qB0, qB1;
  {
    const unsigned short* qp = Q + kbase + (size_t)(qrowA + lane16) * HEAD_DIM + g * 8;
    qA0 = *(const bf16x8*)qp;
    qA1 = *(const bf16x8*)(qp + 32);
    qp = Q + kbase + (size_t)(qrowB + lane16) * HEAD_DIM + g * 8;
    qB0 = *(const bf16x8*)qp;
    qB1 = *(const bf16x8*)(qp + 32);
  }

  const int ci0 = w * 64 + lane;
  const int ci1 = ci0 + 256;
  const int r0 = ci0 >> 3, j0 = (ci0 & 7) ^ (r0 & 7);
  const int r1 = ci1 >> 3, j1 = (ci1 & 7) ^ (r1 & 7);
  const unsigned short* kS0 = Kbase + r0 * HEAD_DIM + j0 * 8;
  const unsigned short* kS1 = Kbase + r1 * HEAD_DIM + j1 * 8;
  const unsigned short* vS0 = Vtbase + (size_t)r0 * S + j0 * 8;
  const unsigned short* vS1 = Vtbase + (size_t)r1 * S + j1 * 8;
  unsigned short* kD0 = Ks + ci0 * 8;
  unsigned short* kD1 = Ks + ci1 * 8;
  unsigned short* vD0 = Vs + ci0 * 8;
  unsigned short* vD1 = Vs + ci1 * 8;

  auto stage = [&](int t, int bi) {
    int koff = t * 4096;
    int voff = t * 64;
    int doff = bi * 4096;
    async16(kS0 + koff, kD0 + doff);
    async16(kS1 + koff, kD1 + doff);
    async16(vS0 + voff, vD0 + doff);
    async16(vS1 + voff, vD1 + doff);
  };

  const floatx4 vzero = {0.f, 0.f, 0.f, 0.f};
  floatx4 oA[4], oB[4];
#pragma unroll
  for (int i = 0; i < 4; i++) { oA[i] = vzero; oB[i] = vzero; }
  float lA = 0.f, lB = 0.f;

  // prologue: 3 tiles in flight
  stage(0, 0);
  __builtin_amdgcn_sched_barrier(0);
  if (qb >= 1) stage(1, 1);
  __builtin_amdgcn_sched_barrier(0);
  if (qb >= 2) stage(2, 2);
  __builtin_amdgcn_sched_barrier(0);

  for (int t = 0; t <= qb; ++t) {
    const int bi = t & 3;
    const int rem = qb - t;
    // wait only for tile t's 4 loads (oldest group); keep rest in flight
    if (rem >= 2)      asm volatile("s_waitcnt vmcnt(8)" ::: "memory");
    else if (rem == 1) asm volatile("s_waitcnt vmcnt(4)" ::: "memory");
    else               asm volatile("s_waitcnt vmcnt(0)" ::: "memory");
    __builtin_amdgcn_sched_barrier(0);
    __builtin_amdgcn_s_barrier();
    __builtin_amdgcn_sched_barrier(0);
    if (t + 3 <= qb) stage(t + 3, (t + 3) & 3);
    __builtin_amdgcn_sched_barrier(0);

    const unsigned short* Kb_ = Ks + bi * 4096;
    const unsigned short* Vb_ = Vs + bi * 4096;
    const bool doA = (t <= qa);

    // shared K fragments (8 ds_read_b128 serve both q-tiles)
    bf16x8 kf0[4], kf1[4];
#pragma unroll
    for (int c = 0; c < 4; ++c) {
      int rr = c * 16 + lane16;
      kf0[c] = *(const bf16x8*)&Kb_[(rr * 8 + (g ^ sw)) * 8];
      kf1[c] = *(const bf16x8*)&Kb_[(rr * 8 + ((4 + g) ^ sw)) * 8];
    }

    floatx4 scB[4];
    __builtin_amdgcn_s_setprio(1);
#pragma unroll
    for (int c = 0; c < 4; ++c) {
      floatx4 s = vzero;
      s = __builtin_amdgcn_mfma_f32_16x16x32_bf16(kf0[c], qB0, s, 0, 0, 0);
      s = __builtin_amdgcn_mfma_f32_16x16x32_bf16(kf1[c], qB1, s, 0, 0, 0);
      scB[c] = s;
    }
    __builtin_amdgcn_s_setprio(0);
    if (t == qb) {
      const int i = qrowB + lane16;
      const int jb = t * 64;
#pragma unroll
      for (int c = 0; c < 4; ++c)
#pragma unroll
        for (int r = 0; r < 4; ++r)
          if (jb + c * 16 + g * 4 + r > i) scB[c][r] = -INFINITY;
    }
    shortx4 pcB[4], pcA[4];
#pragma unroll
    for (int c = 0; c < 4; ++c) {
      float p0 = EXP2(scB[c][0]);
      float p1 = EXP2(scB[c][1]);
      float p2 = EXP2(scB[c][2]);
      float p3 = EXP2(scB[c][3]);
      lB += (p0 + p1) + (p2 + p3);
      union { unsigned int u[2]; shortx4 s4; } pu;
      pu.u[0] = __builtin_amdgcn_perm(__float_as_uint(p1), __float_as_uint(p0), 0x07060302u);
      pu.u[1] = __builtin_amdgcn_perm(__float_as_uint(p3), __float_as_uint(p2), 0x07060302u);
      pcB[c] = pu.s4;
    }

    if (doA) {
      floatx4 scA[4];
      __builtin_amdgcn_s_setprio(1);
#pragma unroll
      for (int c = 0; c < 4; ++c) {
        floatx4 s = vzero;
        s = __builtin_amdgcn_mfma_f32_16x16x32_bf16(kf0[c], qA0, s, 0, 0, 0);
        s = __builtin_amdgcn_mfma_f32_16x16x32_bf16(kf1[c], qA1, s, 0, 0, 0);
        scA[c] = s;
      }
      __builtin_amdgcn_s_setprio(0);
      if (t == qa) {
        const int i = qrowA + lane16;
        const int jb = t * 64;
#pragma unroll
        for (int c = 0; c < 4; ++c)
#pragma unroll
          for (int r = 0; r < 4; ++r)
            if (jb + c * 16 + g * 4 + r > i) scA[c][r] = -INFINITY;
      }
#pragma unroll
      for (int c = 0; c < 4; ++c) {
        float p0 = EXP2(scA[c][0]);
        float p1 = EXP2(scA[c][1]);
        float p2 = EXP2(scA[c][2]);
        float p3 = EXP2(scA[c][3]);
        lA += (p0 + p1) + (p2 + p3);
        union { unsigned int u[2]; shortx4 s4; } pu;
        pu.u[0] = __builtin_amdgcn_perm(__float_as_uint(p1), __float_as_uint(p0), 0x07060302u);
        pu.u[1] = __builtin_amdgcn_perm(__float_as_uint(p3), __float_as_uint(p2), 0x07060302u);
        pcA[c] = pu.s4;
      }
      // PV for both tiles: each vf ds_read feeds TWO mfmas
      __builtin_amdgcn_s_setprio(1);
#pragma unroll
      for (int nt = 0; nt < 4; ++nt) {
        int rv = nt * 16 + lane16;
#pragma unroll
        for (int c = 0; c < 4; ++c) {
          shortx4 vf = *(const shortx4*)&Vb_[(rv * 8 + ((c * 2 + (g >> 1)) ^ sw)) * 8 + (g & 1) * 4];
          oB[nt] = __builtin_amdgcn_mfma_f32_16x16x16bf16_1k(vf, pcB[c], oB[nt], 0, 0, 0);
          oA[nt] = __builtin_amdgcn_mfma_f32_16x16x16bf16_1k(vf, pcA[c], oA[nt], 0, 0, 0);
        }
      }
      __builtin_amdgcn_s_setprio(0);
    } else {
      __builtin_amdgcn_s_setprio(1);
#pragma unroll
      for (int nt = 0; nt < 4; ++nt) {
        int rv = nt * 16 + lane16;
#pragma unroll
        for (int c = 0; c < 4; ++c) {
          shortx4 vf = *(const shortx4*)&Vb_[(rv * 8 + ((c * 2 + (g >> 1)) ^ sw)) * 8 + (g & 1) * 4];
          oB[nt] = __builtin_amdgcn_mfma_f32_16x16x16bf16_1k(vf, pcB[c], oB[nt], 0, 0, 0);
        }
      }
      __builtin_amdgcn_s_setprio(0);
    }
  }

  // epilogue: reduce l over g-groups, normalize, store bf16
  {
    float l = lA;
    l += __shfl_xor(l, 16, 64);
    l += __shfl_xor(l, 32, 64);
    float inv = 1.0f / l;
    int srow = qrowA + lane16;
    size_t rowb = ((size_t)b * S + srow) * 1024 + h * 64;
#pragma unroll
    for (int nt = 0; nt < 4; ++nt) {
      shortx4 st;
#pragma unroll
      for (int r = 0; r < 4; ++r) st[r] = (short)f2b(oA[nt][r] * inv);
      *(shortx4*)&Oattn[rowb + nt * 16 + g * 4] = st;
    }
  }
  {
    float l = lB;
    l += __shfl_xor(l, 16, 64);
    l += __shfl_xor(l, 32, 64);
    float inv = 1.0f / l;
    int srow = qrowB + lane16;
    size_t rowb = ((size_t)b * S + srow) * 1024 + h * 64;
#pragma unroll
    for (int nt = 0; nt < 4; ++nt) {
      shortx4 st;
#pragma unroll
      for (int r = 0; r < 4; ++r) st[r] = (short)f2b(oB[nt][r] * inv);
      *(shortx4*)&Oattn[rowb + nt * 16 + g * 4] = st;
    }
  }
}

// ---------------- launcher ----------------
extern "C" void kernel_launch(void* const* d_in, const int* in_sizes, int n_in,
                              void* d_out, int out_size, void* d_ws, size_t ws_size,
                              hipStream_t stream) {
  const float* x  = (const float*)d_in[0];
  const int*  pos = (const int*)d_in[1];
  const float* wq = (const float*)d_in[2];
  const float* wk = (const float*)d_in[3];
  const float* wv = (const float*)d_in[4];
  const float* wo = (const float*)d_in[5];

  const int D = 1024;
  const int S = in_sizes[1];
  const int M = in_sizes[0] / D;       // B*S
  const int B = M / S;
  const int BH = B * NUM_HEADS;

  char* wsb = (char*)d_ws;
  size_t off = 0;
  auto alloc = [&](size_t bytes) {
    char* p = wsb + off;
    off += (bytes + 255) & ~(size_t)255;
    return p;
  };
  unsigned short* Xb   = (unsigned short*)alloc((size_t)M * D * 2);
  unsigned short* Wqb  = (unsigned short*)alloc((size_t)D * D * 2);
  unsigned short* Wkb  = (unsigned short*)alloc((size_t)D * D * 2);
  unsigned short* Wvb  = (unsigned short*)alloc((size_t)D * D * 2);
  unsigned short* Wob  = (unsigned short*)alloc((size_t)D * D * 2);
  unsigned short* Qb   = (unsigned short*)alloc((size_t)M * D * 2);
  unsigned short* Kb   = (unsigned short*)alloc((size_t)M * D * 2);
  unsigned short* Vtb  = (unsigned short*)alloc((size_t)M * D * 2);  // transposed V
  unsigned short* Attn = (unsigned short*)alloc((size_t)M * D * 2);
  float*          Ctab = (float*)alloc((size_t)S * 32 * 2 * 4);
  (void)ws_size;

  {
    int n4x = M * D / 4;
    int xq = n4x / 4;                 // z=0 threads (4 reps each)
    int w4 = D * D / 4;
    int ntab = S * 32;
    int gx = (w4 + 255) / 256;        // >= xq/256 and >= ntab/256
    prep<<<dim3(gx, 6), 256, 0, stream>>>(x, wq, wk, wv, wo, pos,
                                          Xb, Wqb, Wkb, Wvb, Wob, Ctab,
                                          xq, w4, ntab);
  }
  // QKV projections (BK=64 2-half k-loop); z==2 writes V transposed.
  gemm_bt<0, 128><<<dim3(D / 128, M / 128, 3), 256, 0, stream>>>(
      Xb, Wqb, Wkb, Wvb, Qb, Kb, Vtb, Ctab, M, D, D, S);
  // paired causal flash attention, span-balanced qa remap -> (B*S, D) bf16
  flash_attn7<<<dim3(S / 128, BH), 256, 0, stream>>>(Qb, Kb, Vtb, Attn, S);
  // output projection (64-row tiles -> 512 blocks = 2/CU) -> fp32 d_out
  gemm_bt<1, 64><<<dim3(D / 128, M / 64, 1), 256, 0, stream>>>(
      Attn, Wob, Wob, Wob, d_out, d_out, d_out, Ctab, M, D, D, S);
}